// Round 17
// baseline (397.292 us; speedup 1.0000x reference)
//
#include <hip/hip_runtime.h>
#include <cstdint>
#include <cstddef>

#define B_ 256
#define T_ 250
#define D_ 700
#define KP 704
#define H_ 1024
#define O_ 35
#define NT 22    // 704/32 K-tiles
#define MPAD 256 // padded rows per batch (t 0..249 valid)

typedef __attribute__((ext_vector_type(8))) short s16x8;
typedef __attribute__((ext_vector_type(4))) float fx4;

__device__ __forceinline__ unsigned short f2bf(float v) {
    union { float f; unsigned int u; } a; a.f = v;
    unsigned int r = a.u + 0x7FFFu + ((a.u >> 16) & 1u);
    return (unsigned short)(r >> 16);
}

__device__ __forceinline__ void glds16(const void* g, void* l) {
    __builtin_amdgcn_global_load_lds(
        (const __attribute__((address_space(1))) unsigned int*)g,
        (__attribute__((address_space(3))) unsigned int*)l, 16, 0, 0);
}

// exact convX split math: 8 fp32 (k-order) -> hi s16x8 + lo s16x8 (RNE both)
__device__ __forceinline__ void split8(float4 va, float4 vb, s16x8& hi8, s16x8& lo8) {
    float v[8] = {va.x, va.y, va.z, va.w, vb.x, vb.y, vb.z, vb.w};
    union { unsigned int u[4]; s16x8 s; } Hu, Lu;
#pragma unroll
    for (int j = 0; j < 4; ++j) {
        unsigned short h0 = f2bf(v[2 * j]), h1 = f2bf(v[2 * j + 1]);
        union { unsigned int u; float f; } a0, a1;
        a0.u = ((unsigned int)h0) << 16; a1.u = ((unsigned int)h1) << 16;
        unsigned short l0 = f2bf(v[2 * j] - a0.f), l1 = f2bf(v[2 * j + 1] - a1.f);
        Hu.u[j] = (unsigned int)h0 | ((unsigned int)h1 << 16);
        Lu.u[j] = (unsigned int)l0 | ((unsigned int)l1 << 16);
    }
    hi8 = Hu.s; lo8 = Lu.s;
}

// ---------------------------------------------------------------------------
// Split W_dense -> bf16 hi/lo, TRANSPOSED: WhT/WlT [1024][704], k>=700 zero.
// Also zeroes the 16B zbuf (tail source for gemm1's A staging).
// ---------------------------------------------------------------------------
__global__ __launch_bounds__(256)
void convW(const float* __restrict__ Wd, unsigned short* __restrict__ WhT,
           unsigned short* __restrict__ WlT, float* __restrict__ zbuf)
{
    __shared__ float tile[32][33];
    const int tx = threadIdx.x, ty = threadIdx.y;
    const int bx = blockIdx.x, by = blockIdx.y;
    if (bx == 0 && by == 0 && tx < 4 && ty == 0) zbuf[tx] = 0.f;
#pragma unroll
    for (int i = 0; i < 4; ++i) {
        int k = by * 32 + ty + i * 8;
        int n = bx * 32 + tx;
        tile[ty + i * 8][tx] = (k < D_) ? Wd[(size_t)k * H_ + n] : 0.f;
    }
    __syncthreads();
#pragma unroll
    for (int i = 0; i < 4; ++i) {
        int n = bx * 32 + ty + i * 8;
        int k = by * 32 + tx;
        float v = tile[tx][ty + i * 8];
        unsigned short h = f2bf(v);
        union { unsigned int u; float f; } hf; hf.u = ((unsigned int)h) << 16;
        unsigned short lo = f2bf(v - hf.f);
        WhT[(size_t)n * KP + k] = h;
        WlT[(size_t)n * KP + k] = lo;
    }
}

// ---------------------------------------------------------------------------
// GEMM1 + fused membrane scan + fused x-split (in-register).
// A staged as RAW fp32 from x via global_load_lds into two 64B-row k-halves
// (same byte geometry/swizzle as the old bf16 Ah tile -> conflict-free).
// hi/lo bf16 split happens at fragment-read time with exact f2bf RNE ->
// ah/al bit-identical to convX's output -> d and spike bits bit-identical.
// Schedule (R13 best state): A double-buffer + B triple-buffer = 160KB LDS,
// ONE s_barrier/tile, counted vmcnt(4) at tile start. Tail: tile 21 logical
// quad 3 (k 700-703) sourced from zbuf; rows>=250 clamp to row 249 (garbage
// rows dumped to LDS but never read by the scan).
// ---------------------------------------------------------------------------
__global__ __launch_bounds__(512, 1)
void gemm1(const float* __restrict__ X,
           const unsigned short* __restrict__ Bhp, const unsigned short* __restrict__ Blp,
           const float* __restrict__ bias, const float* __restrict__ tau,
           const float* __restrict__ mem0, const float* __restrict__ spk0,
           unsigned long long* __restrict__ bits, const float* __restrict__ zbuf)
{
    extern __shared__ char smem[];   // A: 2x32KB @0; B: 3x32KB @65536; 160KB
    const int tid = threadIdx.x;
    const int l = tid & 63, w = tid >> 6;
    const int wm = w >> 2, wn = w & 3;          // 2 x 4 wave grid

    // bijective XCD swizzle (nwg = 1024 -> q=128, r=0)
    const int nwg = gridDim.x, orig = blockIdx.x;
    const int xcd = orig & 7, idx = orig >> 3;
    const int q = nwg >> 3, r = nwg & 7;
    const int swz = (xcd < r ? xcd * (q + 1) : r * (q + 1) + (xcd - r) * q) + idx;
    const int by = swz >> 2, bx = swz & 3;      // by = batch b, bx = n-block
    const int n0 = bx * 256;

    // ---- A staging source (fp32 x direct, pre-swizzled quads) ----
    const int rr = tid >> 2, ss = tid & 3;
    const int rrow1 = (rr + 128 <= 249) ? rr + 128 : 249;
    const int lq0 = ss ^ ((rr >> 1) & 3);
    const int lq1 = ss ^ ((rrow1 >> 1) & 3);
    const float* pA0 = X + (size_t)(by * T_ + rr) * D_ + lq0 * 4;
    const float* pA1 = X + (size_t)(by * T_ + rrow1) * D_ + lq1 * 4;
    const bool tl0 = (lq0 == 3), tl1 = (lq1 == 3);

    // ---- B staging source offsets (elements), pre-swizzled slot ----
    const int sw8 = ((ss ^ ((rr >> 1) & 3)) << 3);
    const int offB = (n0 + rr) * KP + sw8;      // j=1 adds 128*KP
    const int wbase = w * 1024;                  // bytes

    // ---- fragment read base offsets ----
    const int ra0 = wm * 128 + (l & 15);
    const int rb0 = wn * 64 + (l & 15);
    const int swzA = (ra0 >> 1) & 3;
    const int g = l >> 4;
    // A: half h=g>>1 (16KB), row ra0 (64B rows), stored quad (2*(g&1))^swzA
    const int aP = (g >> 1) * 16384 + ra0 * 64 + (((2 * (g & 1)) ^ swzA) << 4);
    const int bHb = rb0 * 64 + ((g ^ ((rb0 >> 1) & 3)) << 4);

    fx4 acc[8][4];
#pragma unroll
    for (int i = 0; i < 8; ++i)
#pragma unroll
        for (int j = 0; j < 4; ++j) acc[i][j] = (fx4)0.f;

    auto stageA = [&](int buf, int t) {
        char* base = smem + buf * 32768 + wbase;
        const int kf = t * 32;
        glds16(pA0 + kf, base);                       // khalf0 rows 0-127
        glds16(pA1 + kf, base + 8192);                // khalf0 rows 128-255
        const float* s2 = (t == 21 && tl0) ? zbuf : pA0 + kf + 16;
        const float* s3 = (t == 21 && tl1) ? zbuf : pA1 + kf + 16;
        glds16(s2, base + 16384);                     // khalf1 rows 0-127
        glds16(s3, base + 24576);                     // khalf1 rows 128-255
    };
    auto stageB = [&](int bufB, int t) {
        char* base = smem + 65536 + bufB * 32768 + wbase;
        const int k = t * 32;
        glds16(Bhp + offB + k, base);
        glds16(Bhp + offB + 128 * KP + k, base + 8192);
        glds16(Blp + offB + k, base + 16384);
        glds16(Blp + offB + 128 * KP + k, base + 24576);
    };

    // prologue: B(0)->Bbuf0, B(1)->Bbuf1, A(0)->Abuf0; drain all
    stageB(0, 0);
    stageB(1, 1);
    stageA(0, 0);
    asm volatile("s_waitcnt vmcnt(0)" ::: "memory");
    __builtin_amdgcn_s_barrier();

    for (int t = 0; t < NT; ++t) {
        const char* ab = smem + (t & 1) * 32768;
        const char* bb = smem + 65536 + (t % 3) * 32768;
        s16x8 ah0[4], al0[4], ah1[4], al1[4], bh[4], bl[4];
        float4 fa[4], fb[4];

        // tile-start counted vmcnt: A(t) done; B(t+1) may stay in flight
        if (t + 1 < NT) {
            asm volatile("s_waitcnt vmcnt(4)" ::: "memory");
        } else {
            asm volatile("s_waitcnt vmcnt(0)" ::: "memory");
        }
        __builtin_amdgcn_sched_barrier(0);

        // ---- A fp32 pair reads (rows base..+63) + bh reads; stage A(t+1) ----
#pragma unroll
        for (int f = 0; f < 4; ++f) {
            int o = aP + f * 1024;
            fa[f] = *(const float4*)(ab + o);
            fb[f] = *(const float4*)(ab + (o ^ 16));
            bh[f] = *(const s16x8*)(bb + bHb + f * 1024);
        }
        if (t + 1 < NT) stageA((t + 1) & 1, t + 1);

        // ---- convert -> ah0/al0 (exact f2bf; both from one read) ----
#pragma unroll
        for (int f = 0; f < 4; ++f) split8(fa[f], fb[f], ah0[f], al0[f]);

        // ---- bl reads issued ahead ----
#pragma unroll
        for (int f = 0; f < 4; ++f)
            bl[f] = *(const s16x8*)(bb + 16384 + bHb + f * 1024);

        __builtin_amdgcn_s_setprio(1);
#pragma unroll
        for (int fm = 0; fm < 4; ++fm)
#pragma unroll
            for (int fn = 0; fn < 4; ++fn)
                acc[fm][fn] = __builtin_amdgcn_mfma_f32_16x16x32_bf16(ah0[fm], bh[fn], acc[fm][fn], 0, 0, 0);
        __builtin_amdgcn_s_setprio(0);

        // ---- A fp32 pair reads (rows +64..+127) issued ahead ----
#pragma unroll
        for (int f = 0; f < 4; ++f) {
            int o = aP + 4096 + f * 1024;
            fa[f] = *(const float4*)(ab + o);
            fb[f] = *(const float4*)(ab + (o ^ 16));
        }
        __builtin_amdgcn_s_setprio(1);
#pragma unroll
        for (int fm = 0; fm < 4; ++fm)
#pragma unroll
            for (int fn = 0; fn < 4; ++fn) {
                acc[fm][fn] = __builtin_amdgcn_mfma_f32_16x16x32_bf16(ah0[fm], bl[fn], acc[fm][fn], 0, 0, 0);
                acc[fm][fn] = __builtin_amdgcn_mfma_f32_16x16x32_bf16(al0[fm], bh[fn], acc[fm][fn], 0, 0, 0);
            }
        __builtin_amdgcn_s_setprio(0);

        // ---- convert -> ah1/al1 ----
#pragma unroll
        for (int f = 0; f < 4; ++f) split8(fa[f], fb[f], ah1[f], al1[f]);
        __builtin_amdgcn_sched_barrier(0);

        // ---- issue stage B(t+2) into Bbuf[(t+2)%3] (no reader conflict) ----
        if (t + 2 < NT) stageB((t + 2) % 3, t + 2);

        // ---- MFMA hh (fm4-7) ----
        __builtin_amdgcn_s_setprio(1);
#pragma unroll
        for (int fm = 0; fm < 4; ++fm)
#pragma unroll
            for (int fn = 0; fn < 4; ++fn)
                acc[fm + 4][fn] = __builtin_amdgcn_mfma_f32_16x16x32_bf16(ah1[fm], bh[fn], acc[fm + 4][fn], 0, 0, 0);
        __builtin_amdgcn_s_setprio(0);

        // ---- MFMA hl+lh (fm4-7); register-only ----
        __builtin_amdgcn_s_setprio(1);
#pragma unroll
        for (int fm = 0; fm < 4; ++fm)
#pragma unroll
            for (int fn = 0; fn < 4; ++fn) {
                acc[fm + 4][fn] = __builtin_amdgcn_mfma_f32_16x16x32_bf16(ah1[fm], bl[fn], acc[fm + 4][fn], 0, 0, 0);
                acc[fm + 4][fn] = __builtin_amdgcn_mfma_f32_16x16x32_bf16(al1[fm], bh[fn], acc[fm + 4][fn], 0, 0, 0);
            }
        __builtin_amdgcn_s_setprio(0);
        __builtin_amdgcn_sched_barrier(0);
        __builtin_amdgcn_s_barrier();   // single tile-end barrier
    }

    // ---- fused epilogue: d -> LDS t-chunks -> membrane scan -> spike bits ----
    float bv[4];
#pragma unroll
    for (int fn = 0; fn < 4; ++fn) bv[fn] = bias[n0 + wn * 64 + fn * 16 + (l & 15)];

    float* dl = (float*)smem;   // [128 t-rows][256 cols] fp32 = 128 KB
    const int bb2 = by;
    const int lane = tid & 63;

    float memv = 0.f, spkv = 0.f, alh = 0.f, omh = 0.f;
    unsigned long long* bp = nullptr;
    if (tid < 256) {
        const int h = n0 + tid;
        alh = 1.f / (1.f + expf(-tau[h]));
        omh = 1.f - alh;
        memv = mem0[bb2 * H_ + h];
        spkv = spk0[bb2 * H_ + h];
        bp = bits + (((size_t)bb2 * T_) << 4) + (h >> 6);
    }

#pragma unroll 1
    for (int ck = 0; ck < 2; ++ck) {
        __syncthreads();
        if (wm == ck) {
            const int colb = wn * 64;
#pragma unroll
            for (int fm = 0; fm < 8; ++fm) {
#pragma unroll
                for (int fn = 0; fn < 4; ++fn) {
                    int col = colb + fn * 16 + (l & 15);
#pragma unroll
                    for (int rg = 0; rg < 4; ++rg) {
                        int row = fm * 16 + (l >> 4) * 4 + rg;
                        dl[row * 256 + (col ^ (((row >> 2) & 1) << 4))] = acc[fm][fn][rg] + bv[fn];
                    }
                }
            }
        }
        __syncthreads();
        if (tid < 256) {
            const int nsteps = ck ? (T_ - 128) : 128;
            const int tbase = ck * 128;
            int ttl = 0;
            for (; ttl + 8 <= nsteps; ttl += 8) {
                float dr[8];
#pragma unroll
                for (int j = 0; j < 8; ++j) {
                    int rj = ttl + j;
                    dr[j] = dl[rj * 256 + (tid ^ (((rj >> 2) & 1) << 4))];
                }
#pragma unroll
                for (int j = 0; j < 8; ++j) {
                    memv = memv * alh + omh * dr[j] - spkv;
                    bool fire = (memv - 1.f) > 0.f;
                    spkv = fire ? 1.f : 0.f;
                    unsigned long long msk = __ballot(fire);
                    if (lane == 0) bp[(size_t)(tbase + ttl + j) << 4] = msk;
                }
            }
            for (; ttl < nsteps; ++ttl) {
                float d = dl[ttl * 256 + (tid ^ (((ttl >> 2) & 1) << 4))];
                memv = memv * alh + omh * d - spkv;
                bool fire = (memv - 1.f) > 0.f;
                spkv = fire ? 1.f : 0.f;
                unsigned long long msk = __ballot(fire);
                if (lane == 0) bp[(size_t)(tbase + ttl) << 4] = msk;
            }
        }
    }
}

// ---------------------------------------------------------------------------
// Fused output pass: one block per b (1024 threads, 956 active for rows).
// ---------------------------------------------------------------------------
__global__ __launch_bounds__(1024)
void out_fused(const unsigned long long* __restrict__ bits,
               const float* __restrict__ Wo, const float* __restrict__ bo,
               float* __restrict__ out)
{
    __shared__ float sp[239][37];
    __shared__ float part[64][36];
    const int tid = threadIdx.x;
    const int b = blockIdx.x;
    const int rrow = tid >> 2;
    const int q = tid & 3;

    if (rrow < 239) {
        const int t = rrow + 11;
        float lg[35];
#pragma unroll
        for (int o = 0; o < 35; ++o) lg[o] = (q == 0) ? bo[o] : 0.f;
        const unsigned long long* bp = bits + ((size_t)(b * T_ + t) << 4) + q * 4;
#pragma unroll
        for (int w2 = 0; w2 < 4; ++w2) {
            unsigned long long wb = bp[w2];
            const float* wbase = Wo + (size_t)((q * 4 + w2) * 64) * O_;
            while (wb) {
                int i = __builtin_ctzll(wb);
                wb &= wb - 1;
                const float* wr = wbase + i * O_;
#pragma unroll
                for (int o = 0; o < 35; ++o) lg[o] += wr[o];
            }
        }
#pragma unroll
        for (int o = 0; o < 35; ++o) lg[o] += __shfl_xor(lg[o], 1);
#pragma unroll
        for (int o = 0; o < 35; ++o) lg[o] += __shfl_xor(lg[o], 2);
        float mx = lg[0];
#pragma unroll
        for (int o = 1; o < 35; ++o) mx = fmaxf(mx, lg[o]);
        float sum = 0.f;
#pragma unroll
        for (int o = 0; o < 35; ++o) { lg[o] = expf(lg[o] - mx); sum += lg[o]; }
        float inv = 1.f / sum;
#pragma unroll
        for (int o = 0; o < 35; ++o) if (o / 9 == q) sp[rrow][o] = lg[o] * inv;
    }
    __syncthreads();
    if (tid < 256) {
        const int rl = tid >> 2, qq = tid & 3;
        float a9[9];
#pragma unroll
        for (int j = 0; j < 9; ++j) a9[j] = 0.f;
        for (int c = 0; c < 239; c += 64) {
            int i = c + rl;
            if (i < 239) {
#pragma unroll
                for (int j = 0; j < 9; ++j) if (j < 8 || qq < 3) a9[j] += sp[i][qq * 9 + j];
            }
        }
#pragma unroll
        for (int j = 0; j < 9; ++j) if (j < 8 || qq < 3) part[rl][qq * 9 + j] = a9[j];
    }
    __syncthreads();
    if (tid < 35) {
        float a = 0.f;
        for (int rr = 0; rr < 64; ++rr) a += part[rr][tid];
        out[b * O_ + tid] = a;
    }
}

// ---------------------------------------------------------------------------
extern "C" void kernel_launch(void* const* d_in, const int* in_sizes, int n_in,
                              void* d_out, int out_size, void* d_ws, size_t ws_size,
                              hipStream_t stream) {
    const float* x    = (const float*)d_in[0];
    const float* Wd   = (const float*)d_in[1];
    const float* bd   = (const float*)d_in[2];
    const float* Wo   = (const float*)d_in[3];
    const float* bo   = (const float*)d_in[4];
    const float* tau  = (const float*)d_in[5];
    const float* mem0 = (const float*)d_in[6];
    const float* spk0 = (const float*)d_in[7];
    float* out = (float*)d_out;

    char* ws = (char*)d_ws;
    size_t off = 0;
    auto take = [&](size_t bytes) -> void* {
        void* p = ws + off;
        off = (off + bytes + 255) & ~(size_t)255;
        return p;
    };

    unsigned long long* bits = (unsigned long long*)take((size_t)B_ * T_ * 16 * 8);
    unsigned short* WhT = (unsigned short*)take((size_t)H_ * KP * 2);
    unsigned short* WlT = (unsigned short*)take((size_t)H_ * KP * 2);
    float* zbuf = (float*)take(256);

    // allow 160 KB dynamic LDS for gemm1 (idempotent; ignore error)
    (void)hipFuncSetAttribute((const void*)gemm1,
                              hipFuncAttributeMaxDynamicSharedMemorySize, 163840);

    convW<<<dim3(32, 22), dim3(32, 8), 0, stream>>>(Wd, WhT, WlT, zbuf);
    gemm1<<<B_ * 4, 512, 163840, stream>>>(x, WhT, WlT, bd, tau, mem0, spk0, bits, zbuf);
    out_fused<<<B_, 1024, 0, stream>>>(bits, Wo, bo, out);
}

// Round 18
// 328.838 us; speedup vs baseline: 1.2082x; 1.2082x over previous
//
#include <hip/hip_runtime.h>
#include <cstdint>
#include <cstddef>

#define B_ 256
#define T_ 250
#define D_ 700
#define KP 704
#define H_ 1024
#define O_ 35
#define NT 22    // 704/32 K-tiles
#define MPAD 256 // padded rows per batch (t 0..249 valid)

typedef __attribute__((ext_vector_type(8))) short s16x8;
typedef __attribute__((ext_vector_type(4))) float fx4;

__device__ __forceinline__ unsigned short f2bf(float v) {
    union { float f; unsigned int u; } a; a.f = v;
    unsigned int r = a.u + 0x7FFFu + ((a.u >> 16) & 1u);
    return (unsigned short)(r >> 16);
}

__device__ __forceinline__ void glds16(const unsigned short* g, void* l) {
    __builtin_amdgcn_global_load_lds(
        (const __attribute__((address_space(1))) unsigned int*)(const void*)g,
        (__attribute__((address_space(3))) unsigned int*)l, 16, 0, 0);
}

// ---------------------------------------------------------------------------
// Split W_dense -> bf16 hi/lo, TRANSPOSED: WhT/WlT [1024][704], k>=700 zero.
// ---------------------------------------------------------------------------
__global__ __launch_bounds__(256)
void convW(const float* __restrict__ Wd, unsigned short* __restrict__ WhT,
           unsigned short* __restrict__ WlT)
{
    __shared__ float tile[32][33];
    const int tx = threadIdx.x, ty = threadIdx.y;
    const int bx = blockIdx.x, by = blockIdx.y;
#pragma unroll
    for (int i = 0; i < 4; ++i) {
        int k = by * 32 + ty + i * 8;
        int n = bx * 32 + tx;
        tile[ty + i * 8][tx] = (k < D_) ? Wd[(size_t)k * H_ + n] : 0.f;
    }
    __syncthreads();
#pragma unroll
    for (int i = 0; i < 4; ++i) {
        int n = bx * 32 + ty + i * 8;
        int k = by * 32 + tx;
        float v = tile[tx][ty + i * 8];
        unsigned short h = f2bf(v);
        union { unsigned int u; float f; } hf; hf.u = ((unsigned int)h) << 16;
        unsigned short lo = f2bf(v - hf.f);
        WhT[(size_t)n * KP + k] = h;
        WlT[(size_t)n * KP + k] = lo;
    }
}

// ---------------------------------------------------------------------------
// Split x -> bf16 hi/lo packed rows, PADDED layout [b*256 + tt][704].
// Grid-stride (2048 blocks); explicit float4 loads.
// ---------------------------------------------------------------------------
__global__ __launch_bounds__(256)
void convX(const float* __restrict__ X, unsigned short* __restrict__ xh,
           unsigned short* __restrict__ xl)
{
    const int total = B_ * T_ * 88;
    for (int idx = blockIdx.x * 256 + threadIdx.x; idx < total;
         idx += gridDim.x * 256) {
        int m = idx / 88, s = idx - m * 88;
        int k = s * 8;
        int b = m / T_, tt = m - b * T_;
        const float* row = X + (size_t)m * D_;
        float4 vA = *reinterpret_cast<const float4*>(row + k);
        float4 vB = (k + 4 < D_) ? *reinterpret_cast<const float4*>(row + k + 4)
                                 : make_float4(0.f, 0.f, 0.f, 0.f);
        float v[8] = {vA.x, vA.y, vA.z, vA.w, vB.x, vB.y, vB.z, vB.w};
        unsigned int hw[4], lw[4];
#pragma unroll
        for (int j = 0; j < 4; ++j) {
            unsigned short h0 = f2bf(v[2 * j]), h1 = f2bf(v[2 * j + 1]);
            union { unsigned int u; float f; } a0, a1;
            a0.u = ((unsigned int)h0) << 16; a1.u = ((unsigned int)h1) << 16;
            unsigned short l0 = f2bf(v[2 * j] - a0.f), l1 = f2bf(v[2 * j + 1] - a1.f);
            hw[j] = (unsigned int)h0 | ((unsigned int)h1 << 16);
            lw[j] = (unsigned int)l0 | ((unsigned int)l1 << 16);
        }
        size_t drow = (size_t)(b * MPAD + tt) * KP + k;
        *reinterpret_cast<uint4*>(xh + drow) = make_uint4(hw[0], hw[1], hw[2], hw[3]);
        *reinterpret_cast<uint4*>(xl + drow) = make_uint4(lw[0], lw[1], lw[2], lw[3]);
    }
}

// ---------------------------------------------------------------------------
// GEMM1 + fused membrane scan (R13/R16 measured-best state, UNCHANGED).
// A double-buffer (64KB) + B TRIPLE buffer (96KB) = 160KB LDS -> ONE
// s_barrier per tile. Counted vmcnt(4) at tile start. stageA(t+1) at P1,
// stageB(t+2) mid-tile into Bbuf[(t+2)%3]. Per-acc MFMA order hh->hl->lh
// -> d and spike bits bit-identical. Epilogue: t-chunked LDS scan.
// ---------------------------------------------------------------------------
__global__ __launch_bounds__(512, 1)
void gemm1(const unsigned short* __restrict__ Ahp, const unsigned short* __restrict__ Alp,
           const unsigned short* __restrict__ Bhp, const unsigned short* __restrict__ Blp,
           const float* __restrict__ bias, const float* __restrict__ tau,
           const float* __restrict__ mem0, const float* __restrict__ spk0,
           unsigned long long* __restrict__ bits)
{
    extern __shared__ char smem[];   // A: 2x32KB @0; B: 3x32KB @65536; 160KB
    const int tid = threadIdx.x;
    const int l = tid & 63, w = tid >> 6;
    const int wm = w >> 2, wn = w & 3;          // 2 x 4 wave grid

    // bijective XCD swizzle (nwg = 1024 -> q=128, r=0)
    const int nwg = gridDim.x, orig = blockIdx.x;
    const int xcd = orig & 7, idx = orig >> 3;
    const int q = nwg >> 3, r = nwg & 7;
    const int swz = (xcd < r ? xcd * (q + 1) : r * (q + 1) + (xcd - r) * q) + idx;
    const int by = swz >> 2, bx = swz & 3;      // by = batch b, bx = n-block
    const int m0 = by * MPAD, n0 = bx * 256;

    // ---- staging source offsets (elements), pre-swizzled slot in 64B row ----
    const int rr = tid >> 2, ss = tid & 3;
    const int sw8 = ((ss ^ ((rr >> 1) & 3)) << 3);
    const int offA = (m0 + rr) * KP + sw8;      // j=1 adds 128*KP
    const int offB = (n0 + rr) * KP + sw8;
    const int wbase = w * 1024;                  // bytes

    // ---- fragment read base offsets (bytes within a 32KB buffer) ----
    const int ra0 = wm * 128 + (l & 15);
    const int rb0 = wn * 64 + (l & 15);
    const int aHb = ra0 * 64 + (((l >> 4) ^ ((ra0 >> 1) & 3)) << 4);
    const int bHb = rb0 * 64 + (((l >> 4) ^ ((rb0 >> 1) & 3)) << 4);

    fx4 acc[8][4];
#pragma unroll
    for (int i = 0; i < 8; ++i)
#pragma unroll
        for (int j = 0; j < 4; ++j) acc[i][j] = (fx4)0.f;

    auto stageA = [&](int buf, int t) {
        char* base = smem + buf * 32768 + wbase;
        const int k = t * 32;
        glds16(Ahp + offA + k, base);
        glds16(Ahp + offA + 128 * KP + k, base + 8192);
        glds16(Alp + offA + k, base + 16384);
        glds16(Alp + offA + 128 * KP + k, base + 24576);
    };
    auto stageB = [&](int bufB, int t) {
        char* base = smem + 65536 + bufB * 32768 + wbase;
        const int k = t * 32;
        glds16(Bhp + offB + k, base);
        glds16(Bhp + offB + 128 * KP + k, base + 8192);
        glds16(Blp + offB + k, base + 16384);
        glds16(Blp + offB + 128 * KP + k, base + 24576);
    };

    // prologue: B(0)->Bbuf0, B(1)->Bbuf1, A(0)->Abuf0; drain all
    stageB(0, 0);
    stageB(1, 1);
    stageA(0, 0);
    asm volatile("s_waitcnt vmcnt(0)" ::: "memory");
    __builtin_amdgcn_s_barrier();

    for (int t = 0; t < NT; ++t) {
        const char* ab = smem + (t & 1) * 32768;
        const char* bb = smem + 65536 + (t % 3) * 32768;
        s16x8 ah0[4], al0[4], ah1[4], al1[4], bh[4], bl[4];

        // tile-start counted vmcnt: A(t) done; B(t+1) may stay in flight
        if (t + 1 < NT) {
            asm volatile("s_waitcnt vmcnt(4)" ::: "memory");
        } else {
            asm volatile("s_waitcnt vmcnt(0)" ::: "memory");
        }
        __builtin_amdgcn_sched_barrier(0);

        // ---- reads for P1 (ah0, bh); issue stage A(t+1) ----
#pragma unroll
        for (int f = 0; f < 4; ++f) {
            ah0[f] = *(const s16x8*)(ab + aHb + f * 1024);
            bh[f]  = *(const s16x8*)(bb + bHb + f * 1024);
        }
        if (t + 1 < NT) stageA((t + 1) & 1, t + 1);

        // ---- reads for P2 (al0, bl) issued ahead ----
#pragma unroll
        for (int f = 0; f < 4; ++f) {
            al0[f] = *(const s16x8*)(ab + 16384 + aHb + f * 1024);
            bl[f]  = *(const s16x8*)(bb + 16384 + bHb + f * 1024);
        }
        __builtin_amdgcn_s_setprio(1);
#pragma unroll
        for (int fm = 0; fm < 4; ++fm)
#pragma unroll
            for (int fn = 0; fn < 4; ++fn)
                acc[fm][fn] = __builtin_amdgcn_mfma_f32_16x16x32_bf16(ah0[fm], bh[fn], acc[fm][fn], 0, 0, 0);
        __builtin_amdgcn_s_setprio(0);

        // ---- reads for P3 (ah1, al1) issued ahead ----
#pragma unroll
        for (int f = 0; f < 4; ++f) {
            ah1[f] = *(const s16x8*)(ab + aHb + 4096 + f * 1024);
            al1[f] = *(const s16x8*)(ab + 16384 + aHb + 4096 + f * 1024);
        }
        __builtin_amdgcn_s_setprio(1);
#pragma unroll
        for (int fm = 0; fm < 4; ++fm)
#pragma unroll
            for (int fn = 0; fn < 4; ++fn) {
                acc[fm][fn] = __builtin_amdgcn_mfma_f32_16x16x32_bf16(ah0[fm], bl[fn], acc[fm][fn], 0, 0, 0);
                acc[fm][fn] = __builtin_amdgcn_mfma_f32_16x16x32_bf16(al0[fm], bh[fn], acc[fm][fn], 0, 0, 0);
            }
        __builtin_amdgcn_s_setprio(0);
        __builtin_amdgcn_sched_barrier(0);

        // ---- issue stage B(t+2) into Bbuf[(t+2)%3] (no reader conflict) ----
        if (t + 2 < NT) stageB((t + 2) % 3, t + 2);

        // ---- P3: MFMA hh (fm4-7) ----
        __builtin_amdgcn_s_setprio(1);
#pragma unroll
        for (int fm = 0; fm < 4; ++fm)
#pragma unroll
            for (int fn = 0; fn < 4; ++fn)
                acc[fm + 4][fn] = __builtin_amdgcn_mfma_f32_16x16x32_bf16(ah1[fm], bh[fn], acc[fm + 4][fn], 0, 0, 0);
        __builtin_amdgcn_s_setprio(0);

        // ---- P4: MFMA hl+lh (fm4-7); register-only ----
        __builtin_amdgcn_s_setprio(1);
#pragma unroll
        for (int fm = 0; fm < 4; ++fm)
#pragma unroll
            for (int fn = 0; fn < 4; ++fn) {
                acc[fm + 4][fn] = __builtin_amdgcn_mfma_f32_16x16x32_bf16(ah1[fm], bl[fn], acc[fm + 4][fn], 0, 0, 0);
                acc[fm + 4][fn] = __builtin_amdgcn_mfma_f32_16x16x32_bf16(al1[fm], bh[fn], acc[fm + 4][fn], 0, 0, 0);
            }
        __builtin_amdgcn_s_setprio(0);
        __builtin_amdgcn_sched_barrier(0);
        __builtin_amdgcn_s_barrier();   // single tile-end barrier
    }

    // ---- fused epilogue: d -> LDS t-chunks -> membrane scan -> spike bits ----
    float bv[4];
#pragma unroll
    for (int fn = 0; fn < 4; ++fn) bv[fn] = bias[n0 + wn * 64 + fn * 16 + (l & 15)];

    float* dl = (float*)smem;   // [128 t-rows][256 cols] fp32 = 128 KB
    const int bb2 = by;
    const int lane = tid & 63;

    // per-thread scan state: threads tid<256 own column h = n0 + tid
    float memv = 0.f, spkv = 0.f, alh = 0.f, omh = 0.f;
    unsigned long long* bp = nullptr;
    if (tid < 256) {
        const int h = n0 + tid;
        alh = 1.f / (1.f + expf(-tau[h]));
        omh = 1.f - alh;
        memv = mem0[bb2 * H_ + h];
        spkv = spk0[bb2 * H_ + h];
        bp = bits + (((size_t)bb2 * T_) << 4) + (h >> 6);
    }

#pragma unroll 1
    for (int ck = 0; ck < 2; ++ck) {
        __syncthreads();   // LDS free (K-loop done / prev scan done)
        if (wm == ck) {    // wm0 waves hold t-rows 0..127; wm1 rows 128..255
            const int colb = wn * 64;
#pragma unroll
            for (int fm = 0; fm < 8; ++fm) {
#pragma unroll
                for (int fn = 0; fn < 4; ++fn) {
                    int col = colb + fn * 16 + (l & 15);
#pragma unroll
                    for (int rg = 0; rg < 4; ++rg) {
                        int row = fm * 16 + (l >> 4) * 4 + rg;
                        dl[row * 256 + (col ^ (((row >> 2) & 1) << 4))] = acc[fm][fn][rg] + bv[fn];
                    }
                }
            }
        }
        __syncthreads();
        if (tid < 256) {
            const int nsteps = ck ? (T_ - 128) : 128;
            const int tbase = ck * 128;
            int ttl = 0;
            for (; ttl + 8 <= nsteps; ttl += 8) {
                float dr[8];
#pragma unroll
                for (int j = 0; j < 8; ++j) {
                    int rj = ttl + j;
                    dr[j] = dl[rj * 256 + (tid ^ (((rj >> 2) & 1) << 4))];
                }
#pragma unroll
                for (int j = 0; j < 8; ++j) {
                    memv = memv * alh + omh * dr[j] - spkv;
                    bool fire = (memv - 1.f) > 0.f;
                    spkv = fire ? 1.f : 0.f;
                    unsigned long long msk = __ballot(fire);
                    if (lane == 0) bp[(size_t)(tbase + ttl + j) << 4] = msk;
                }
            }
            for (; ttl < nsteps; ++ttl) {
                float d = dl[ttl * 256 + (tid ^ (((ttl >> 2) & 1) << 4))];
                memv = memv * alh + omh * d - spkv;
                bool fire = (memv - 1.f) > 0.f;
                spkv = fire ? 1.f : 0.f;
                unsigned long long msk = __ballot(fire);
                if (lane == 0) bp[(size_t)(tbase + ttl) << 4] = msk;
            }
        }
    }
}

// ---------------------------------------------------------------------------
// Fused output pass: one block per b (1024 threads, 956 active for rows).
// ---------------------------------------------------------------------------
__global__ __launch_bounds__(1024)
void out_fused(const unsigned long long* __restrict__ bits,
               const float* __restrict__ Wo, const float* __restrict__ bo,
               float* __restrict__ out)
{
    __shared__ float sp[239][37];
    __shared__ float part[64][36];
    const int tid = threadIdx.x;
    const int b = blockIdx.x;
    const int rrow = tid >> 2;
    const int q = tid & 3;

    if (rrow < 239) {
        const int t = rrow + 11;
        float lg[35];
#pragma unroll
        for (int o = 0; o < 35; ++o) lg[o] = (q == 0) ? bo[o] : 0.f;
        const unsigned long long* bp = bits + ((size_t)(b * T_ + t) << 4) + q * 4;
#pragma unroll
        for (int w2 = 0; w2 < 4; ++w2) {
            unsigned long long wb = bp[w2];
            const float* wbase = Wo + (size_t)((q * 4 + w2) * 64) * O_;
            while (wb) {
                int i = __builtin_ctzll(wb);
                wb &= wb - 1;
                const float* wr = wbase + i * O_;
#pragma unroll
                for (int o = 0; o < 35; ++o) lg[o] += wr[o];
            }
        }
#pragma unroll
        for (int o = 0; o < 35; ++o) lg[o] += __shfl_xor(lg[o], 1);
#pragma unroll
        for (int o = 0; o < 35; ++o) lg[o] += __shfl_xor(lg[o], 2);
        float mx = lg[0];
#pragma unroll
        for (int o = 1; o < 35; ++o) mx = fmaxf(mx, lg[o]);
        float sum = 0.f;
#pragma unroll
        for (int o = 0; o < 35; ++o) { lg[o] = expf(lg[o] - mx); sum += lg[o]; }
        float inv = 1.f / sum;
#pragma unroll
        for (int o = 0; o < 35; ++o) if (o / 9 == q) sp[rrow][o] = lg[o] * inv;
    }
    __syncthreads();
    if (tid < 256) {
        const int rl = tid >> 2, qq = tid & 3;
        float a9[9];
#pragma unroll
        for (int j = 0; j < 9; ++j) a9[j] = 0.f;
        for (int c = 0; c < 239; c += 64) {
            int i = c + rl;
            if (i < 239) {
#pragma unroll
                for (int j = 0; j < 9; ++j) if (j < 8 || qq < 3) a9[j] += sp[i][qq * 9 + j];
            }
        }
#pragma unroll
        for (int j = 0; j < 9; ++j) if (j < 8 || qq < 3) part[rl][qq * 9 + j] = a9[j];
    }
    __syncthreads();
    if (tid < 35) {
        float a = 0.f;
        for (int rr = 0; rr < 64; ++rr) a += part[rr][tid];
        out[b * O_ + tid] = a;
    }
}

// ---------------------------------------------------------------------------
extern "C" void kernel_launch(void* const* d_in, const int* in_sizes, int n_in,
                              void* d_out, int out_size, void* d_ws, size_t ws_size,
                              hipStream_t stream) {
    const float* x    = (const float*)d_in[0];
    const float* Wd   = (const float*)d_in[1];
    const float* bd   = (const float*)d_in[2];
    const float* Wo   = (const float*)d_in[3];
    const float* bo   = (const float*)d_in[4];
    const float* tau  = (const float*)d_in[5];
    const float* mem0 = (const float*)d_in[6];
    const float* spk0 = (const float*)d_in[7];
    float* out = (float*)d_out;

    char* ws = (char*)d_ws;
    size_t off = 0;
    auto take = [&](size_t bytes) -> void* {
        void* p = ws + off;
        off = (off + bytes + 255) & ~(size_t)255;
        return p;
    };

    unsigned long long* bits = (unsigned long long*)take((size_t)B_ * T_ * 16 * 8);
    unsigned short* WhT = (unsigned short*)take((size_t)H_ * KP * 2);
    unsigned short* WlT = (unsigned short*)take((size_t)H_ * KP * 2);
    unsigned short* xh = (unsigned short*)take((size_t)B_ * MPAD * KP * 2);
    unsigned short* xl = (unsigned short*)take((size_t)B_ * MPAD * KP * 2);

    // allow 160 KB dynamic LDS for gemm1 (idempotent; ignore error)
    (void)hipFuncSetAttribute((const void*)gemm1,
                              hipFuncAttributeMaxDynamicSharedMemorySize, 163840);

    convW<<<dim3(32, 22), dim3(32, 8), 0, stream>>>(Wd, WhT, WlT);
    convX<<<2048, 256, 0, stream>>>(x, xh, xl);
    gemm1<<<B_ * 4, 512, 163840, stream>>>(xh, xl, WhT, WlT, bd, tau, mem0, spk0, bits);
    out_fused<<<B_, 1024, 0, stream>>>(bits, Wo, bo, out);
}

// Round 19
// 325.993 us; speedup vs baseline: 1.2187x; 1.0087x over previous
//
#include <hip/hip_runtime.h>
#include <cstdint>
#include <cstddef>

#define B_ 256
#define T_ 250
#define D_ 700
#define KP 704
#define H_ 1024
#define O_ 35
#define NT 22    // 704/32 K-tiles
#define MPAD 256 // padded rows per batch (t 0..249 valid)

typedef __attribute__((ext_vector_type(8))) short s16x8;
typedef __attribute__((ext_vector_type(4))) float fx4;

__device__ __forceinline__ unsigned short f2bf(float v) {
    union { float f; unsigned int u; } a; a.f = v;
    unsigned int r = a.u + 0x7FFFu + ((a.u >> 16) & 1u);
    return (unsigned short)(r >> 16);
}

__device__ __forceinline__ void glds16(const unsigned short* g, void* l) {
    __builtin_amdgcn_global_load_lds(
        (const __attribute__((address_space(1))) unsigned int*)(const void*)g,
        (__attribute__((address_space(3))) unsigned int*)l, 16, 0, 0);
}

// ---------------------------------------------------------------------------
// Split W_dense -> bf16 hi/lo, TRANSPOSED: WhT/WlT [1024][704], k>=700 zero.
// ---------------------------------------------------------------------------
__global__ __launch_bounds__(256)
void convW(const float* __restrict__ Wd, unsigned short* __restrict__ WhT,
           unsigned short* __restrict__ WlT)
{
    __shared__ float tile[32][33];
    const int tx = threadIdx.x, ty = threadIdx.y;
    const int bx = blockIdx.x, by = blockIdx.y;
#pragma unroll
    for (int i = 0; i < 4; ++i) {
        int k = by * 32 + ty + i * 8;
        int n = bx * 32 + tx;
        tile[ty + i * 8][tx] = (k < D_) ? Wd[(size_t)k * H_ + n] : 0.f;
    }
    __syncthreads();
#pragma unroll
    for (int i = 0; i < 4; ++i) {
        int n = bx * 32 + ty + i * 8;
        int k = by * 32 + tx;
        float v = tile[tx][ty + i * 8];
        unsigned short h = f2bf(v);
        union { unsigned int u; float f; } hf; hf.u = ((unsigned int)h) << 16;
        unsigned short lo = f2bf(v - hf.f);
        WhT[(size_t)n * KP + k] = h;
        WlT[(size_t)n * KP + k] = lo;
    }
}

// ---------------------------------------------------------------------------
// Split x -> bf16 hi/lo packed rows, PADDED layout [b*256 + tt][704].
// Explicit float4 loads (16B/ld, aligned: row base m*2800B and k*4 are 16B).
// ---------------------------------------------------------------------------
__global__ __launch_bounds__(256)
void convX(const float* __restrict__ X, unsigned short* __restrict__ xh,
           unsigned short* __restrict__ xl)
{
    int idx = blockIdx.x * 256 + threadIdx.x;
    if (idx >= B_ * T_ * 88) return;
    int m = idx / 88, s = idx - m * 88;
    int k = s * 8;
    int b = m / T_, tt = m - b * T_;
    const float* row = X + (size_t)m * D_;
    float4 vA = *reinterpret_cast<const float4*>(row + k);
    float4 vB = (k + 4 < D_) ? *reinterpret_cast<const float4*>(row + k + 4)
                             : make_float4(0.f, 0.f, 0.f, 0.f);
    float v[8] = {vA.x, vA.y, vA.z, vA.w, vB.x, vB.y, vB.z, vB.w};
    unsigned int hw[4], lw[4];
#pragma unroll
    for (int j = 0; j < 4; ++j) {
        unsigned short h0 = f2bf(v[2 * j]), h1 = f2bf(v[2 * j + 1]);
        union { unsigned int u; float f; } a0, a1;
        a0.u = ((unsigned int)h0) << 16; a1.u = ((unsigned int)h1) << 16;
        unsigned short l0 = f2bf(v[2 * j] - a0.f), l1 = f2bf(v[2 * j + 1] - a1.f);
        hw[j] = (unsigned int)h0 | ((unsigned int)h1 << 16);
        lw[j] = (unsigned int)l0 | ((unsigned int)l1 << 16);
    }
    size_t drow = (size_t)(b * MPAD + tt) * KP + k;
    *reinterpret_cast<uint4*>(xh + drow) = make_uint4(hw[0], hw[1], hw[2], hw[3]);
    *reinterpret_cast<uint4*>(xl + drow) = make_uint4(lw[0], lw[1], lw[2], lw[3]);
}

// ---------------------------------------------------------------------------
// GEMM1 + fused membrane scan (measured-best state). K-loop: A double-buffer
// (64KB) + B TRIPLE buffer (96KB) = 160KB LDS -> ONE s_barrier per tile.
// Counted vmcnt(4) at tile start (waits A(t), leaves B(t+1) in flight).
// stageA(t+1) at P1, stageB(t+2) mid-tile into Bbuf[(t+2)%3]. Per-acc MFMA
// order hh->hl->lh -> d and spike bits bit-identical across rounds.
// Occupancy note: acc(128 AGPR) + ~128 VGPR = 256 regs/thread caps HW at
// 2 waves/SIMD regardless of LDS -> the 48% MfmaUtil plateau is structural.
// Epilogue: t-chunked LDS scan with 8-deep ds_read prefetch.
// ---------------------------------------------------------------------------
__global__ __launch_bounds__(512, 1)
void gemm1(const unsigned short* __restrict__ Ahp, const unsigned short* __restrict__ Alp,
           const unsigned short* __restrict__ Bhp, const unsigned short* __restrict__ Blp,
           const float* __restrict__ bias, const float* __restrict__ tau,
           const float* __restrict__ mem0, const float* __restrict__ spk0,
           unsigned long long* __restrict__ bits)
{
    extern __shared__ char smem[];   // A: 2x32KB @0; B: 3x32KB @65536; 160KB
    const int tid = threadIdx.x;
    const int l = tid & 63, w = tid >> 6;
    const int wm = w >> 2, wn = w & 3;          // 2 x 4 wave grid

    // bijective XCD swizzle (nwg = 1024 -> q=128, r=0)
    const int nwg = gridDim.x, orig = blockIdx.x;
    const int xcd = orig & 7, idx = orig >> 3;
    const int q = nwg >> 3, r = nwg & 7;
    const int swz = (xcd < r ? xcd * (q + 1) : r * (q + 1) + (xcd - r) * q) + idx;
    const int by = swz >> 2, bx = swz & 3;      // by = batch b, bx = n-block
    const int m0 = by * MPAD, n0 = bx * 256;

    // ---- staging source offsets (elements), pre-swizzled slot in 64B row ----
    const int rr = tid >> 2, ss = tid & 3;
    const int sw8 = ((ss ^ ((rr >> 1) & 3)) << 3);
    const int offA = (m0 + rr) * KP + sw8;      // j=1 adds 128*KP
    const int offB = (n0 + rr) * KP + sw8;
    const int wbase = w * 1024;                  // bytes

    // ---- fragment read base offsets (bytes within a 32KB buffer) ----
    const int ra0 = wm * 128 + (l & 15);
    const int rb0 = wn * 64 + (l & 15);
    const int aHb = ra0 * 64 + (((l >> 4) ^ ((ra0 >> 1) & 3)) << 4);
    const int bHb = rb0 * 64 + (((l >> 4) ^ ((rb0 >> 1) & 3)) << 4);

    fx4 acc[8][4];
#pragma unroll
    for (int i = 0; i < 8; ++i)
#pragma unroll
        for (int j = 0; j < 4; ++j) acc[i][j] = (fx4)0.f;

    auto stageA = [&](int buf, int t) {
        char* base = smem + buf * 32768 + wbase;
        const int k = t * 32;
        glds16(Ahp + offA + k, base);
        glds16(Ahp + offA + 128 * KP + k, base + 8192);
        glds16(Alp + offA + k, base + 16384);
        glds16(Alp + offA + 128 * KP + k, base + 24576);
    };
    auto stageB = [&](int bufB, int t) {
        char* base = smem + 65536 + bufB * 32768 + wbase;
        const int k = t * 32;
        glds16(Bhp + offB + k, base);
        glds16(Bhp + offB + 128 * KP + k, base + 8192);
        glds16(Blp + offB + k, base + 16384);
        glds16(Blp + offB + 128 * KP + k, base + 24576);
    };

    // prologue: B(0)->Bbuf0, B(1)->Bbuf1, A(0)->Abuf0; drain all
    stageB(0, 0);
    stageB(1, 1);
    stageA(0, 0);
    asm volatile("s_waitcnt vmcnt(0)" ::: "memory");
    __builtin_amdgcn_s_barrier();

    for (int t = 0; t < NT; ++t) {
        const char* ab = smem + (t & 1) * 32768;
        const char* bb = smem + 65536 + (t % 3) * 32768;
        s16x8 ah0[4], al0[4], ah1[4], al1[4], bh[4], bl[4];

        // tile-start counted vmcnt: A(t) done; B(t+1) may stay in flight
        if (t + 1 < NT) {
            asm volatile("s_waitcnt vmcnt(4)" ::: "memory");
        } else {
            asm volatile("s_waitcnt vmcnt(0)" ::: "memory");
        }
        __builtin_amdgcn_sched_barrier(0);

        // ---- reads for P1 (ah0, bh); issue stage A(t+1) ----
#pragma unroll
        for (int f = 0; f < 4; ++f) {
            ah0[f] = *(const s16x8*)(ab + aHb + f * 1024);
            bh[f]  = *(const s16x8*)(bb + bHb + f * 1024);
        }
        if (t + 1 < NT) stageA((t + 1) & 1, t + 1);

        // ---- reads for P2 (al0, bl) issued ahead ----
#pragma unroll
        for (int f = 0; f < 4; ++f) {
            al0[f] = *(const s16x8*)(ab + 16384 + aHb + f * 1024);
            bl[f]  = *(const s16x8*)(bb + 16384 + bHb + f * 1024);
        }
        __builtin_amdgcn_s_setprio(1);
#pragma unroll
        for (int fm = 0; fm < 4; ++fm)
#pragma unroll
            for (int fn = 0; fn < 4; ++fn)
                acc[fm][fn] = __builtin_amdgcn_mfma_f32_16x16x32_bf16(ah0[fm], bh[fn], acc[fm][fn], 0, 0, 0);
        __builtin_amdgcn_s_setprio(0);

        // ---- reads for P3 (ah1, al1) issued ahead ----
#pragma unroll
        for (int f = 0; f < 4; ++f) {
            ah1[f] = *(const s16x8*)(ab + aHb + 4096 + f * 1024);
            al1[f] = *(const s16x8*)(ab + 16384 + aHb + 4096 + f * 1024);
        }
        __builtin_amdgcn_s_setprio(1);
#pragma unroll
        for (int fm = 0; fm < 4; ++fm)
#pragma unroll
            for (int fn = 0; fn < 4; ++fn) {
                acc[fm][fn] = __builtin_amdgcn_mfma_f32_16x16x32_bf16(ah0[fm], bl[fn], acc[fm][fn], 0, 0, 0);
                acc[fm][fn] = __builtin_amdgcn_mfma_f32_16x16x32_bf16(al0[fm], bh[fn], acc[fm][fn], 0, 0, 0);
            }
        __builtin_amdgcn_s_setprio(0);
        __builtin_amdgcn_sched_barrier(0);

        // ---- issue stage B(t+2) into Bbuf[(t+2)%3] (no reader conflict) ----
        if (t + 2 < NT) stageB((t + 2) % 3, t + 2);

        // ---- P3: MFMA hh (fm4-7) ----
        __builtin_amdgcn_s_setprio(1);
#pragma unroll
        for (int fm = 0; fm < 4; ++fm)
#pragma unroll
            for (int fn = 0; fn < 4; ++fn)
                acc[fm + 4][fn] = __builtin_amdgcn_mfma_f32_16x16x32_bf16(ah1[fm], bh[fn], acc[fm + 4][fn], 0, 0, 0);
        __builtin_amdgcn_s_setprio(0);

        // ---- P4: MFMA hl+lh (fm4-7); register-only ----
        __builtin_amdgcn_s_setprio(1);
#pragma unroll
        for (int fm = 0; fm < 4; ++fm)
#pragma unroll
            for (int fn = 0; fn < 4; ++fn) {
                acc[fm + 4][fn] = __builtin_amdgcn_mfma_f32_16x16x32_bf16(ah1[fm], bl[fn], acc[fm + 4][fn], 0, 0, 0);
                acc[fm + 4][fn] = __builtin_amdgcn_mfma_f32_16x16x32_bf16(al1[fm], bh[fn], acc[fm + 4][fn], 0, 0, 0);
            }
        __builtin_amdgcn_s_setprio(0);
        __builtin_amdgcn_sched_barrier(0);
        __builtin_amdgcn_s_barrier();   // single tile-end barrier
    }

    // ---- fused epilogue: d -> LDS t-chunks -> membrane scan -> spike bits ----
    float bv[4];
#pragma unroll
    for (int fn = 0; fn < 4; ++fn) bv[fn] = bias[n0 + wn * 64 + fn * 16 + (l & 15)];

    float* dl = (float*)smem;   // [128 t-rows][256 cols] fp32 = 128 KB
    const int bb2 = by;
    const int lane = tid & 63;

    // per-thread scan state: threads tid<256 own column h = n0 + tid
    float memv = 0.f, spkv = 0.f, alh = 0.f, omh = 0.f;
    unsigned long long* bp = nullptr;
    if (tid < 256) {
        const int h = n0 + tid;
        alh = 1.f / (1.f + expf(-tau[h]));
        omh = 1.f - alh;
        memv = mem0[bb2 * H_ + h];
        spkv = spk0[bb2 * H_ + h];
        bp = bits + (((size_t)bb2 * T_) << 4) + (h >> 6);
    }

#pragma unroll 1
    for (int ck = 0; ck < 2; ++ck) {
        __syncthreads();   // LDS free (K-loop done / prev scan done)
        if (wm == ck) {    // wm0 waves hold t-rows 0..127; wm1 rows 128..255
            const int colb = wn * 64;
#pragma unroll
            for (int fm = 0; fm < 8; ++fm) {
#pragma unroll
                for (int fn = 0; fn < 4; ++fn) {
                    int col = colb + fn * 16 + (l & 15);
#pragma unroll
                    for (int rg = 0; rg < 4; ++rg) {
                        int row = fm * 16 + (l >> 4) * 4 + rg;
                        dl[row * 256 + (col ^ (((row >> 2) & 1) << 4))] = acc[fm][fn][rg] + bv[fn];
                    }
                }
            }
        }
        __syncthreads();
        if (tid < 256) {
            const int nsteps = ck ? (T_ - 128) : 128;
            const int tbase = ck * 128;
            int ttl = 0;
            for (; ttl + 8 <= nsteps; ttl += 8) {
                float dr[8];
#pragma unroll
                for (int j = 0; j < 8; ++j) {
                    int rj = ttl + j;
                    dr[j] = dl[rj * 256 + (tid ^ (((rj >> 2) & 1) << 4))];
                }
#pragma unroll
                for (int j = 0; j < 8; ++j) {
                    memv = memv * alh + omh * dr[j] - spkv;
                    bool fire = (memv - 1.f) > 0.f;
                    spkv = fire ? 1.f : 0.f;
                    unsigned long long msk = __ballot(fire);
                    if (lane == 0) bp[(size_t)(tbase + ttl + j) << 4] = msk;
                }
            }
            for (; ttl < nsteps; ++ttl) {
                float d = dl[ttl * 256 + (tid ^ (((ttl >> 2) & 1) << 4))];
                memv = memv * alh + omh * d - spkv;
                bool fire = (memv - 1.f) > 0.f;
                spkv = fire ? 1.f : 0.f;
                unsigned long long msk = __ballot(fire);
                if (lane == 0) bp[(size_t)(tbase + ttl) << 4] = msk;
            }
        }
    }
}

// ---------------------------------------------------------------------------
// Fused output pass: one block per b (1024 threads, 956 active for rows).
// ---------------------------------------------------------------------------
__global__ __launch_bounds__(1024)
void out_fused(const unsigned long long* __restrict__ bits,
               const float* __restrict__ Wo, const float* __restrict__ bo,
               float* __restrict__ out)
{
    __shared__ float sp[239][37];
    __shared__ float part[64][36];
    const int tid = threadIdx.x;
    const int b = blockIdx.x;
    const int rrow = tid >> 2;
    const int q = tid & 3;

    if (rrow < 239) {
        const int t = rrow + 11;
        float lg[35];
#pragma unroll
        for (int o = 0; o < 35; ++o) lg[o] = (q == 0) ? bo[o] : 0.f;
        const unsigned long long* bp = bits + ((size_t)(b * T_ + t) << 4) + q * 4;
#pragma unroll
        for (int w2 = 0; w2 < 4; ++w2) {
            unsigned long long wb = bp[w2];
            const float* wbase = Wo + (size_t)((q * 4 + w2) * 64) * O_;
            while (wb) {
                int i = __builtin_ctzll(wb);
                wb &= wb - 1;
                const float* wr = wbase + i * O_;
#pragma unroll
                for (int o = 0; o < 35; ++o) lg[o] += wr[o];
            }
        }
#pragma unroll
        for (int o = 0; o < 35; ++o) lg[o] += __shfl_xor(lg[o], 1);
#pragma unroll
        for (int o = 0; o < 35; ++o) lg[o] += __shfl_xor(lg[o], 2);
        float mx = lg[0];
#pragma unroll
        for (int o = 1; o < 35; ++o) mx = fmaxf(mx, lg[o]);
        float sum = 0.f;
#pragma unroll
        for (int o = 0; o < 35; ++o) { lg[o] = expf(lg[o] - mx); sum += lg[o]; }
        float inv = 1.f / sum;
#pragma unroll
        for (int o = 0; o < 35; ++o) if (o / 9 == q) sp[rrow][o] = lg[o] * inv;
    }
    __syncthreads();
    if (tid < 256) {
        const int rl = tid >> 2, qq = tid & 3;
        float a9[9];
#pragma unroll
        for (int j = 0; j < 9; ++j) a9[j] = 0.f;
        for (int c = 0; c < 239; c += 64) {
            int i = c + rl;
            if (i < 239) {
#pragma unroll
                for (int j = 0; j < 9; ++j) if (j < 8 || qq < 3) a9[j] += sp[i][qq * 9 + j];
            }
        }
#pragma unroll
        for (int j = 0; j < 9; ++j) if (j < 8 || qq < 3) part[rl][qq * 9 + j] = a9[j];
    }
    __syncthreads();
    if (tid < 35) {
        float a = 0.f;
        for (int rr = 0; rr < 64; ++rr) a += part[rr][tid];
        out[b * O_ + tid] = a;
    }
}

// ---------------------------------------------------------------------------
extern "C" void kernel_launch(void* const* d_in, const int* in_sizes, int n_in,
                              void* d_out, int out_size, void* d_ws, size_t ws_size,
                              hipStream_t stream) {
    const float* x    = (const float*)d_in[0];
    const float* Wd   = (const float*)d_in[1];
    const float* bd   = (const float*)d_in[2];
    const float* Wo   = (const float*)d_in[3];
    const float* bo   = (const float*)d_in[4];
    const float* tau  = (const float*)d_in[5];
    const float* mem0 = (const float*)d_in[6];
    const float* spk0 = (const float*)d_in[7];
    float* out = (float*)d_out;

    char* ws = (char*)d_ws;
    size_t off = 0;
    auto take = [&](size_t bytes) -> void* {
        void* p = ws + off;
        off = (off + bytes + 255) & ~(size_t)255;
        return p;
    };

    unsigned long long* bits = (unsigned long long*)take((size_t)B_ * T_ * 16 * 8);
    unsigned short* WhT = (unsigned short*)take((size_t)H_ * KP * 2);
    unsigned short* WlT = (unsigned short*)take((size_t)H_ * KP * 2);
    unsigned short* xh = (unsigned short*)take((size_t)B_ * MPAD * KP * 2);
    unsigned short* xl = (unsigned short*)take((size_t)B_ * MPAD * KP * 2);

    // allow 160 KB dynamic LDS for gemm1 (idempotent; ignore error)
    (void)hipFuncSetAttribute((const void*)gemm1,
                              hipFuncAttributeMaxDynamicSharedMemorySize, 163840);

    convW<<<dim3(32, 22), dim3(32, 8), 0, stream>>>(Wd, WhT, WlT);
    convX<<<(B_ * T_ * 88 + 255) / 256, 256, 0, stream>>>(x, xh, xl);
    gemm1<<<B_ * 4, 512, 163840, stream>>>(xh, xl, WhT, WlT, bd, tau, mem0, spk0, bits);
    out_fused<<<B_, 1024, 0, stream>>>(bits, Wo, bo, out);
}